// Round 3
// baseline (472.350 us; speedup 1.0000x reference)
//
#include <hip/hip_runtime.h>
#include <stdint.h>

#define B_DIM 4
#define Z_DIM 128
#define L_DIM 64
#define P_DIM 65536   // 256*256
#define CHUNK 128     // pixels staged per chunk

typedef short sh8  __attribute__((ext_vector_type(8)));   // 8 bf16 = 16B (MFMA A/B frag)
typedef short sh4v __attribute__((ext_vector_type(4)));   // 4 bf16 = 8B
typedef float f32x4 __attribute__((ext_vector_type(4)));  // MFMA C/D frag

// fp32 -> bf16 RNE
__device__ __forceinline__ unsigned short bfc(float x) {
  uint32_t u = __float_as_uint(x);
  u += 0x7FFFu + ((u >> 16) & 1u);
  return (unsigned short)(u >> 16);
}

// XOR swizzle (guide G4): row stride = 128 ushorts (256B). XOR bits 3..5 of the
// ushort index with (row&7) -> spreads the 16B frag slots of 8 rows across banks.
__device__ __forceinline__ int swz(int row, int k) {
  return (row * CHUNK + k) ^ ((row & 7) << 3);
}

// ---------------------------------------------------------------------------
// Pass 1 (pipelined): fused stream over pred/pred_mv.
//   grid = (NB, 4 batches, 2 views), block = 256 (4 waves).
// Software pipeline per chunk c (T14 async-STAGE):
//   A: barrier (MFMA(c-1) done with LDS)
//      convert rv(c) regs -> masked bf16 tile in LDS; zero onehot; label atomics
//      issue global loads rv(c+1) + meta(c+1)        <- in flight across MFMA
//   B: barrier; set onehot bits from meta(c)
//   C: barrier; MFMA over tile c (Gram + onehot-sums)
// Per-(b,l): n_l (int) and sum|a|^2 (fp32) via LDS atomics, exact path for sim.
// ---------------------------------------------------------------------------
__global__ __launch_bounds__(256, 2)
void pass1_k(const float* __restrict__ pred, const float* __restrict__ predmv,
             const int* __restrict__ gt, const uint8_t* __restrict__ fov,
             float* __restrict__ gpart, float* __restrict__ spart,
             float* __restrict__ qpart, int NB, int nchunks) {
  const int cb = blockIdx.x, b = blockIdx.y, view = blockIdx.z;
  const float* __restrict__ src = (view ? predmv : pred) + (size_t)b * Z_DIM * P_DIM;
  const int* __restrict__ gtb = gt + (size_t)b * P_DIM;
  const uint8_t* __restrict__ fovb = fov + (size_t)b * P_DIM;
  const int t = threadIdx.x;
  const int wid = t >> 6, lane = t & 63;

  __shared__ __align__(16) unsigned short tile[Z_DIM * CHUNK]; // 32 KB
  __shared__ __align__(16) unsigned short oh[L_DIM * CHUNK];   // 16 KB
  __shared__ float sqseg[L_DIM];
  __shared__ int   cnt[L_DIM];

  if (t < L_DIM) { sqseg[t] = 0.f; cnt[t] = 0; }

  f32x4 accg[2][8];  // Gram: rows ti=2*wid+i, cols tj=0..7 (static indexing only)
  f32x4 accs[8];     // S: label-tile wid x z-tiles
  const f32x4 zero4 = {0.f, 0.f, 0.f, 0.f};
#pragma unroll
  for (int i = 0; i < 2; ++i)
#pragma unroll
    for (int j = 0; j < 8; ++j) accg[i][j] = zero4;
#pragma unroll
  for (int j = 0; j < 8; ++j) accs[j] = zero4;

  const int pb0 = cb * (P_DIM / NB);
  const int zr  = t >> 5;          // 0..7 (z row group)
  const int px4 = (t & 31) << 2;   // pixel*4 within chunk

  // ---- prologue: issue chunk 0 loads ----
  float4 rv[16];
  int4   g4;  uchar4 f4;
  {
    const int pb = pb0;
    g4 = *(const int4*)(gtb + pb + px4);
    f4 = *(const uchar4*)(fovb + pb + px4);
#pragma unroll
    for (int r = 0; r < 16; ++r)
      rv[r] = *(const float4*)(src + (size_t)(zr + r * 8) * P_DIM + pb + px4);
  }

  for (int c = 0; c < nchunks; ++c) {
    __syncthreads();  // A: MFMA(c-1) done reading tile/oh

    const float w0 = (f4.x != 0 && g4.x != 0) ? 1.f : 0.f;
    const float w1 = (f4.y != 0 && g4.y != 0) ? 1.f : 0.f;
    const float w2 = (f4.z != 0 && g4.z != 0) ? 1.f : 0.f;
    const float w3 = (f4.w != 0 && g4.w != 0) ? 1.f : 0.f;

    // convert + write masked bf16 tile (waits vmcnt for rv(c) here)
    float s0 = 0.f, s1 = 0.f, s2 = 0.f, s3 = 0.f;
#pragma unroll
    for (int r = 0; r < 16; ++r) {
      const int z = zr + r * 8;
      const float a0 = rv[r].x * w0, a1 = rv[r].y * w1;
      const float a2 = rv[r].z * w2, a3 = rv[r].w * w3;
      s0 += a0 * a0; s1 += a1 * a1; s2 += a2 * a2; s3 += a3 * a3;
      sh4v pk;
      pk.x = (short)bfc(a0); pk.y = (short)bfc(a1);
      pk.z = (short)bfc(a2); pk.w = (short)bfc(a3);
      *(sh4v*)&tile[swz(z, px4)] = pk;
    }
    {  // zero onehot tile (16 KB, 256 thr x 4 uint4)
      uint4* ohv = (uint4*)oh;
      uint4 z4; z4.x = 0u; z4.y = 0u; z4.z = 0u; z4.w = 0u;
#pragma unroll
      for (int i = 0; i < 4; ++i) ohv[t + i * 256] = z4;
    }
    // per-label fp32 sq sums (masked: s_i==0 when w_i==0, skip for traffic)
    if (w0 != 0.f) atomicAdd(&sqseg[g4.x & 63], s0);
    if (w1 != 0.f) atomicAdd(&sqseg[g4.y & 63], s1);
    if (w2 != 0.f) atomicAdd(&sqseg[g4.z & 63], s2);
    if (w3 != 0.f) atomicAdd(&sqseg[g4.w & 63], s3);
    if (zr == 0) {  // n_l counts (one thread group per pixel quad)
      if (w0 != 0.f) atomicAdd(&cnt[g4.x & 63], 1);
      if (w1 != 0.f) atomicAdd(&cnt[g4.y & 63], 1);
      if (w2 != 0.f) atomicAdd(&cnt[g4.z & 63], 1);
      if (w3 != 0.f) atomicAdd(&cnt[g4.w & 63], 1);
    }

    // ---- issue next chunk's loads (in flight across MFMA phase) ----
    int4 g4n = g4; uchar4 f4n = f4;
    if (c + 1 < nchunks) {
      const int pbn = pb0 + (c + 1) * CHUNK;
      g4n = *(const int4*)(gtb + pbn + px4);
      f4n = *(const uchar4*)(fovb + pbn + px4);
#pragma unroll
      for (int r = 0; r < 16; ++r)
        rv[r] = *(const float4*)(src + (size_t)(zr + r * 8) * P_DIM + pbn + px4);
    }

    __syncthreads();  // B: tile written, oh zeroed
    if (zr == 0) {    // set onehot bits for chunk c
      if (w0 != 0.f) oh[swz(g4.x & 63, px4 + 0)] = 0x3F80;
      if (w1 != 0.f) oh[swz(g4.y & 63, px4 + 1)] = 0x3F80;
      if (w2 != 0.f) oh[swz(g4.z & 63, px4 + 2)] = 0x3F80;
      if (w3 != 0.f) oh[swz(g4.w & 63, px4 + 3)] = 0x3F80;
    }
    __syncthreads();  // C: oh set visible

    // ---- MFMA over K=128 (4 ksteps of 32) ----
#pragma unroll
    for (int ks = 0; ks < 4; ++ks) {
      const int kb = ks * 32 + ((lane >> 4) << 3);
      sh8 fz[8], fa[2], ohf;
#pragma unroll
      for (int zt = 0; zt < 8; ++zt)
        fz[zt] = *(const sh8*)&tile[swz(zt * 16 + (lane & 15), kb)];
#pragma unroll
      for (int i = 0; i < 2; ++i)
        fa[i] = *(const sh8*)&tile[swz((2 * wid + i) * 16 + (lane & 15), kb)];
      ohf = *(const sh8*)&oh[swz(wid * 16 + (lane & 15), kb)];
#pragma unroll
      for (int i = 0; i < 2; ++i)
#pragma unroll
        for (int tj = 0; tj < 8; ++tj)
          accg[i][tj] = __builtin_amdgcn_mfma_f32_16x16x32_bf16(fa[i], fz[tj], accg[i][tj], 0, 0, 0);
#pragma unroll
      for (int zt = 0; zt < 8; ++zt)
        accs[zt] = __builtin_amdgcn_mfma_f32_16x16x32_bf16(ohf, fz[zt], accs[zt], 0, 0, 0);
    }

    g4 = g4n; f4 = f4n;  // rotate meta
  }
  __syncthreads();

  // ---- flush partials (upper-triangular Gram tiles only) ----
  const size_t slot = (size_t)(view * 4 + b) * NB + cb;
  float* gp = gpart + slot * (36 * 256);
#pragma unroll
  for (int i = 0; i < 2; ++i) {
    const int ti = 2 * wid + i;
#pragma unroll
    for (int tj = 0; tj < 8; ++tj) {
      if (tj >= ti) {  // wave-uniform branch
        const int lin = ti * 8 - (ti * (ti - 1)) / 2 + (tj - ti);
        float* dst = gp + lin * 256 + (lane >> 4) * 64 + (lane & 15);
#pragma unroll
        for (int r = 0; r < 4; ++r) dst[r * 16] = accg[i][tj][r];
      }
    }
  }
  float* sp = spart + slot * (32 * 256) + wid * (8 * 256);
#pragma unroll
  for (int zt = 0; zt < 8; ++zt) {
    float* dst = sp + zt * 256 + (lane >> 4) * 64 + (lane & 15);
#pragma unroll
    for (int r = 0; r < 4; ++r) dst[r * 16] = accs[zt][r];
  }
  if (t < L_DIM) {
    qpart[slot * 128 + t]          = sqseg[t];
    qpart[slot * 128 + L_DIM + t]  = (float)cnt[t];
  }
}

// ---------------------------------------------------------------------------
// Reduce partial buffers
// gred[2][36][256], sred[2][4][4][8][256], qred[2][4][128]
// ---------------------------------------------------------------------------
__global__ void reduce_k(const float* __restrict__ gpart, const float* __restrict__ spart,
                         const float* __restrict__ qpart, float* __restrict__ gred,
                         float* __restrict__ sred, float* __restrict__ qred, int NB) {
  int id = blockIdx.x * blockDim.x + threadIdx.x;
  const int GE = 2 * 36 * 256, SE = 2 * 4 * 32 * 256, QE = 2 * 4 * 128;
  if (id < GE) {
    const int v = id / (36 * 256), e = id % (36 * 256);
    const float* p = gpart + (size_t)v * 4 * NB * (36 * 256) + e;
    float acc = 0.f;
    for (int s = 0; s < 4 * NB; ++s) acc += p[(size_t)s * (36 * 256)];
    gred[id] = acc;
  } else if ((id -= GE) < SE) {
    const int vb = id / (32 * 256);
    const float* p = spart + (size_t)vb * NB * (32 * 256) + (id % (32 * 256));
    float acc = 0.f;
    for (int s = 0; s < NB; ++s) acc += p[(size_t)s * (32 * 256)];
    sred[id] = acc;
  } else if ((id -= SE) < QE) {
    const int vb = id >> 7;
    const float* p = qpart + (size_t)vb * NB * 128 + (id & 127);
    float acc = 0.f;
    for (int s = 0; s < NB; ++s) acc += p[(size_t)s * 128];
    qred[id] = acc;
  }
}

// ---------------------------------------------------------------------------
// Finalize: sim + std + cov -> single scalar. 1 block x 256 threads, fp64 accum.
// sred index: (((v*4+b)*4 + (l>>4))*8 + (z>>4))*256 + (l&15)*16 + (z&15)
// qred index: (v*4+b)*128 + l  (sq sums) ; (v*4+b)*128 + 64 + l (counts)
// ---------------------------------------------------------------------------
__global__ void finalize_k(const float* __restrict__ gred, const float* __restrict__ sred,
                           const float* __restrict__ qred, float* __restrict__ out) {
  const int t = threadIdx.x;
  __shared__ double red[256];
  __shared__ double mu[2][128];
  __shared__ double scal[8];
  __shared__ int tti[36], ttj[36];
  if (t == 0) {
    int idx = 0;
    for (int ti = 0; ti < 8; ++ti)
      for (int tj = ti; tj < 8; ++tj) { tti[idx] = ti; ttj[idx] = tj; ++idx; }
  }
  const int bb = t >> 6, ll = t & 63;
  const double nlv = (double)qred[bb * 128 + 64 + ll];  // view0 counts

  red[t] = nlv;  // n
  __syncthreads();
  for (int s = 128; s > 0; s >>= 1) { if (t < s) red[t] += red[t + s]; __syncthreads(); }
  if (t == 0) scal[0] = red[0];
  __syncthreads();
  const double n = scal[0];

  red[t] = nlv * nlv;  // count
  __syncthreads();
  for (int s = 128; s > 0; s >>= 1) { if (t < s) red[t] += red[t + s]; __syncthreads(); }
  if (t == 0) scal[1] = red[0];
  __syncthreads();

  {  // sim numerator
    const double sqa = (double)qred[(0 * 4 + bb) * 128 + ll];
    const double sqm = (double)qred[(1 * 4 + bb) * 128 + ll];
    double dot = 0.0;
    for (int z = 0; z < 128; ++z) {
      const int e = ((ll & 15) << 4) + (z & 15);
      const int ia = (((0 * 4 + bb) * 4 + (ll >> 4)) * 8 + (z >> 4)) * 256 + e;
      const int im = (((1 * 4 + bb) * 4 + (ll >> 4)) * 8 + (z >> 4)) * 256 + e;
      dot += (double)sred[ia] * (double)sred[im];
    }
    red[t] = nlv * (sqa + sqm) - 2.0 * dot;
  }
  __syncthreads();
  for (int s = 128; s > 0; s >>= 1) { if (t < s) red[t] += red[t + s]; __syncthreads(); }
  if (t == 0) scal[2] = red[0];
  __syncthreads();

  {  // mu
    const int v = t >> 7, z = t & 127;
    double s = 0.0;
    for (int b = 0; b < 4; ++b)
      for (int l = 0; l < 64; ++l)
        s += (double)sred[(((v * 4 + b) * 4 + (l >> 4)) * 8 + (z >> 4)) * 256 + ((l & 15) << 4) + (z & 15)];
    mu[v][z] = s / n;
  }
  __syncthreads();

  {  // std
    const int v = t >> 7, z = t & 127;
    const int zt = z >> 4;
    const int lin = zt * 8 - (zt * (zt - 1)) / 2;
    const double gd = (double)gred[v * 9216 + lin * 256 + (z & 15) * 17];
    const double var = (gd - n * mu[v][z] * mu[v][z]) / (n - 1.0);
    const double sd = sqrt(var + 1e-4);
    const double rr = 1.0 - sd;
    red[t] = rr > 0.0 ? rr : 0.0;
  }
  __syncthreads();
  for (int s = 64; s > 0; s >>= 1) { if ((t & 127) < s) red[t] += red[t + s]; __syncthreads(); }
  if (t == 0)   scal[3] = red[0] / 128.0;
  if (t == 128) scal[4] = red[128] / 128.0;
  __syncthreads();

  for (int v = 0; v < 2; ++v) {  // cov: 2*sum_{i<j} cov_ij^2 / Z
    double acc = 0.0;
    for (int idx = t; idx < 9216; idx += 256) {
      const int lin = idx >> 8, e = idx & 255;
      const int i = tti[lin] * 16 + (e >> 4), j = ttj[lin] * 16 + (e & 15);
      if (i < j) {
        const double g = (double)gred[v * 9216 + idx];
        const double cv = (g - n * mu[v][i] * mu[v][j]) / (n - 1.0);
        acc += 2.0 * cv * cv;
      }
    }
    red[t] = acc;
    __syncthreads();
    for (int s = 128; s > 0; s >>= 1) { if (t < s) red[t] += red[t + s]; __syncthreads(); }
    if (t == 0) scal[5 + v] = red[0] / 128.0;
    __syncthreads();
  }

  if (t == 0)
    out[0] = (float)(scal[2] / scal[1] + scal[3] + scal[4] + scal[5] + scal[6]);
}

// ---------------------------------------------------------------------------
extern "C" void kernel_launch(void* const* d_in, const int* in_sizes, int n_in,
                              void* d_out, int out_size, void* d_ws, size_t ws_size,
                              hipStream_t stream) {
  const float*  pred   = (const float*)d_in[0];
  const float*  predmv = (const float*)d_in[1];
  const int*    gt     = (const int*)d_in[2];
  const uint8_t* fov   = (const uint8_t*)d_in[3];   // jnp bool = 1 byte/elem
  float* out = (float*)d_out;

  // NB = blocks per (view,batch); shrink if workspace is small.
  int NB = 64;
  const size_t per_slot = 36 * 256 + 32 * 256 + 128;  // floats per block slot
  const size_t reserved = (size_t)(2 * 36 * 256 + 2 * 4 * 32 * 256 + 2 * 4 * 128) * 4 + 1024;
  while (NB > 1 && (size_t)8 * NB * per_slot * 4 + reserved > ws_size) NB >>= 1;

  float* ws    = (float*)d_ws;
  float* gpart = ws;
  float* spart = gpart + (size_t)8 * NB * (36 * 256);
  float* qpart = spart + (size_t)8 * NB * (32 * 256);
  float* gred  = qpart + (size_t)8 * NB * 128;
  float* sred  = gred + 2 * 36 * 256;
  float* qred  = sred + 2 * 4 * 32 * 256;

  pass1_k<<<dim3(NB, 4, 2), dim3(256), 0, stream>>>(pred, predmv, gt, fov,
                                                    gpart, spart, qpart, NB, 512 / NB);
  const int tot = 2 * 36 * 256 + 2 * 4 * 32 * 256 + 2 * 4 * 128;
  reduce_k<<<dim3((tot + 255) / 256), dim3(256), 0, stream>>>(gpart, spart, qpart,
                                                              gred, sred, qred, NB);
  finalize_k<<<dim3(1), dim3(256), 0, stream>>>(gred, sred, qred, out);
}

// Round 5
// 373.616 us; speedup vs baseline: 1.2643x; 1.2643x over previous
//
#include <hip/hip_runtime.h>
#include <stdint.h>

#define B_DIM 4
#define Z_DIM 128
#define L_DIM 64
#define P_DIM 65536   // 256*256
#define CHUNK 64      // pixels staged per chunk

typedef short sh8  __attribute__((ext_vector_type(8)));   // 8 bf16 = 16B (MFMA A/B frag)
typedef short sh4v __attribute__((ext_vector_type(4)));   // 4 bf16 = 8B
typedef float f32x4 __attribute__((ext_vector_type(4)));  // MFMA C/D frag

// fp32 -> bf16 RNE
__device__ __forceinline__ unsigned short bfc(float x) {
  uint32_t u = __float_as_uint(x);
  u += 0x7FFFu + ((u >> 16) & 1u);
  return (unsigned short)(u >> 16);
}

// ushort-index XOR swizzle for [128][64] bf16 tile (row = 64 ushorts = 128B).
// Fragment granule = 8 ushorts (16B); XOR slot bits 3..5 with (row&7) spreads
// 8 consecutive rows across all 32 banks -> column-frag ds_read_b128 balanced.
// Mask bits (3..5) don't intersect intra-granule bits (write 4-ushort, read
// 8-ushort granules), so px<->k mapping round-trips between write & read.
__device__ __forceinline__ int swz64(int row, int k) {
  return row * CHUNK + (k ^ ((row & 7) << 3));
}

// async global->LDS DMA, 16B per lane. LDS dest is wave-uniform base + lane*16;
// global src is per-lane.
#define GLOAD_LDS16(g, l)                                                        \
  __builtin_amdgcn_global_load_lds(                                              \
      (const __attribute__((address_space(1))) void*)(g),                        \
      (__attribute__((address_space(3))) void*)(l), 16, 0, 0)

// ---------------------------------------------------------------------------
// Pass 1: fused stream over pred/pred_mv. grid=(NB,4,2), block=256 (4 waves),
// 1 block/CU. Per chunk of 64 px:
//   top:  issue DMA stage(c+1) -> buf^1 ; s_waitcnt vmcnt(8) (counted, never
//         drains the c+1 queue) ; raw s_barrier
//   cvt:  read fp32 stage[buf], mask, bf16-pack -> swizzled tile; |a|^2 and
//         n_l label atomics in LDS ; lgkmcnt(0) ; raw s_barrier
//   mfma: Gram (8x8 z-tiles, rows 2wid+i) + onehot-sums (label-tile wid),
//         onehot A-frag built in registers from meta (lab|w<<8 per px).
// No VGPR-held prefetch -> no spills. DMA keeps HBM busy during compute.
// ---------------------------------------------------------------------------
__global__ __launch_bounds__(256, 1)
void pass1_k(const float* __restrict__ pred, const float* __restrict__ predmv,
             const int* __restrict__ gt, const uint8_t* __restrict__ fov,
             float* __restrict__ gpart, float* __restrict__ spart,
             float* __restrict__ qpart, int NB, int nch) {
  const int cb = blockIdx.x, b = blockIdx.y, view = blockIdx.z;
  const float* __restrict__ src = (view ? predmv : pred) + (size_t)b * Z_DIM * P_DIM;
  const int* __restrict__ gtb = gt + (size_t)b * P_DIM;
  const uint8_t* __restrict__ fovb = fov + (size_t)b * P_DIM;
  const int t = threadIdx.x;
  const int wid = t >> 6, lane = t & 63;
  const int PPB = nch * CHUNK;          // pixels per block (<= 4096)
  const int pb0 = cb * PPB;

  __shared__ __align__(16) float stage[2][Z_DIM * CHUNK];       // 2 x 32 KB
  __shared__ __align__(16) unsigned short tile[Z_DIM * CHUNK];  // 16 KB
  __shared__ __align__(16) unsigned short meta[4096];           // lab | (w<<8), 8 KB
  __shared__ float sqseg[L_DIM];
  __shared__ int   cnt[L_DIM];

  if (t < L_DIM) { sqseg[t] = 0.f; cnt[t] = 0; }

  f32x4 accg[2][8];  // Gram: row-tiles ti=2*wid+i x col-tiles tj (static idx)
  f32x4 accs[8];     // S: label-tile wid x z-tiles
  const f32x4 zero4 = {0.f, 0.f, 0.f, 0.f};
#pragma unroll
  for (int i = 0; i < 2; ++i)
#pragma unroll
    for (int j = 0; j < 8; ++j) accg[i][j] = zero4;
#pragma unroll
  for (int j = 0; j < 8; ++j) accs[j] = zero4;

  // ---- meta preload: lab | (w<<8) per pixel (consumed before DMA issue) ----
  for (int base = 0; base < PPB; base += 2048) {
    const int pl = base + (t << 3);
    if (pl < PPB) {
      const int4   g0 = *(const int4*)(gtb + pb0 + pl);
      const uchar4 f0 = *(const uchar4*)(fovb + pb0 + pl);
      const int4   g1 = *(const int4*)(gtb + pb0 + pl + 4);
      const uchar4 f1 = *(const uchar4*)(fovb + pb0 + pl + 4);
      sh8 mm;
      mm[0] = (short)(g0.x | ((f0.x && g0.x) ? 256 : 0));
      mm[1] = (short)(g0.y | ((f0.y && g0.y) ? 256 : 0));
      mm[2] = (short)(g0.z | ((f0.z && g0.z) ? 256 : 0));
      mm[3] = (short)(g0.w | ((f0.w && g0.w) ? 256 : 0));
      mm[4] = (short)(g1.x | ((f1.x && g1.x) ? 256 : 0));
      mm[5] = (short)(g1.y | ((f1.y && g1.y) ? 256 : 0));
      mm[6] = (short)(g1.z | ((f1.z && g1.z) ? 256 : 0));
      mm[7] = (short)(g1.w | ((f1.w && g1.w) ? 256 : 0));
      *(sh8*)&meta[pl] = mm;
    }
  }

  // ---- issue DMA for chunk 0 ----
  // instr i covers z-rows wid*32+i*4 .. +3; lane -> (row=l>>4, col16=l&15)
  {
    const float* g0 = src + (size_t)(wid * 32 + (lane >> 4)) * P_DIM + pb0 + ((lane & 15) << 2);
#pragma unroll
    for (int i = 0; i < 8; ++i)
      GLOAD_LDS16(g0 + (size_t)(i * 4) * P_DIM, &stage[0][(wid * 32 + i * 4) * CHUNK]);
  }

  const int zb = t >> 4, sl = t & 15;   // convert mapping: z = zb + 16r, px4 = sl*4

  for (int c = 0; c < nch; ++c) {
    const int buf = c & 1;
    if (c + 1 < nch) {  // issue stage(c+1) into buf^1, then counted wait for c
      const float* g1 = src + (size_t)(wid * 32 + (lane >> 4)) * P_DIM
                        + pb0 + (c + 1) * CHUNK + ((lane & 15) << 2);
#pragma unroll
      for (int i = 0; i < 8; ++i)
        GLOAD_LDS16(g1 + (size_t)(i * 4) * P_DIM, &stage[buf ^ 1][(wid * 32 + i * 4) * CHUNK]);
      asm volatile("s_waitcnt vmcnt(8)" ::: "memory");
    } else {
      asm volatile("s_waitcnt vmcnt(0)" ::: "memory");
    }
    __builtin_amdgcn_s_barrier();          // stage[buf] visible to all waves
    __builtin_amdgcn_sched_barrier(0);

    // ---- convert: fp32 stage -> masked bf16 swizzled tile ----
    const sh4v mm4 = *(const sh4v*)&meta[c * CHUNK + (sl << 2)];
    const int m0 = (unsigned short)mm4.x, m1 = (unsigned short)mm4.y;
    const int m2 = (unsigned short)mm4.z, m3 = (unsigned short)mm4.w;
    const float w0 = (m0 >> 8) ? 1.f : 0.f, w1 = (m1 >> 8) ? 1.f : 0.f;
    const float w2 = (m2 >> 8) ? 1.f : 0.f, w3 = (m3 >> 8) ? 1.f : 0.f;
    float s0 = 0.f, s1 = 0.f, s2 = 0.f, s3 = 0.f;
#pragma unroll
    for (int r = 0; r < 8; ++r) {
      const int z = zb + (r << 4);
      const float4 v = *(const float4*)&stage[buf][z * CHUNK + (sl << 2)];
      const float a0 = v.x * w0, a1 = v.y * w1, a2 = v.z * w2, a3 = v.w * w3;
      s0 += a0 * a0; s1 += a1 * a1; s2 += a2 * a2; s3 += a3 * a3;
      sh4v pk;
      pk.x = (short)bfc(a0); pk.y = (short)bfc(a1);
      pk.z = (short)bfc(a2); pk.w = (short)bfc(a3);
      *(sh4v*)&tile[swz64(z, sl << 2)] = pk;
    }
    if (m0 >> 8) atomicAdd(&sqseg[m0 & 63], s0);
    if (m1 >> 8) atomicAdd(&sqseg[m1 & 63], s1);
    if (m2 >> 8) atomicAdd(&sqseg[m2 & 63], s2);
    if (m3 >> 8) atomicAdd(&sqseg[m3 & 63], s3);
    if (zb == 0) {  // n_l counts, once per pixel
      if (m0 >> 8) atomicAdd(&cnt[m0 & 63], 1);
      if (m1 >> 8) atomicAdd(&cnt[m1 & 63], 1);
      if (m2 >> 8) atomicAdd(&cnt[m2 & 63], 1);
      if (m3 >> 8) atomicAdd(&cnt[m3 & 63], 1);
    }
    asm volatile("s_waitcnt lgkmcnt(0)" ::: "memory");
    __builtin_amdgcn_s_barrier();          // tile writes visible
    __builtin_amdgcn_sched_barrier(0);

    // ---- MFMA over K=64 (2 ksteps of 32) ----
#pragma unroll
    for (int ks = 0; ks < 2; ++ks) {
      const int kb = (ks << 5) + ((lane >> 4) << 3);
      sh8 fz[8], fa[2], ohf;
#pragma unroll
      for (int zt = 0; zt < 8; ++zt)
        fz[zt] = *(const sh8*)&tile[swz64(zt * 16 + (lane & 15), kb)];
#pragma unroll
      for (int i = 0; i < 2; ++i)
        fa[i] = *(const sh8*)&tile[swz64((2 * wid + i) * 16 + (lane & 15), kb)];
      {  // onehot A-frag from meta: value 1.0bf iff lab==row && w
        const sh8 mm = *(const sh8*)&meta[c * CHUNK + kb];
        const short hit = (short)((wid << 4) + (lane & 15) + 256);
#pragma unroll
        for (int j = 0; j < 8; ++j)
          ohf[j] = (mm[j] == hit) ? (short)0x3F80 : (short)0;
      }
#pragma unroll
      for (int i = 0; i < 2; ++i)
#pragma unroll
        for (int tj = 0; tj < 8; ++tj)
          accg[i][tj] = __builtin_amdgcn_mfma_f32_16x16x32_bf16(fa[i], fz[tj], accg[i][tj], 0, 0, 0);
#pragma unroll
      for (int zt = 0; zt < 8; ++zt)
        accs[zt] = __builtin_amdgcn_mfma_f32_16x16x32_bf16(ohf, fz[zt], accs[zt], 0, 0, 0);
    }
  }
  __syncthreads();

  // ---- flush partials (upper-triangular Gram tiles only) ----
  const size_t slot = (size_t)(view * 4 + b) * NB + cb;
  float* gp = gpart + slot * (36 * 256);
#pragma unroll
  for (int i = 0; i < 2; ++i) {
    const int ti = 2 * wid + i;
#pragma unroll
    for (int tj = 0; tj < 8; ++tj) {
      if (tj >= ti) {  // wave-uniform branch
        const int lin = ti * 8 - (ti * (ti - 1)) / 2 + (tj - ti);
        float* dst = gp + lin * 256 + (lane >> 4) * 64 + (lane & 15);
#pragma unroll
        for (int r = 0; r < 4; ++r) dst[r * 16] = accg[i][tj][r];
      }
    }
  }
  float* sp = spart + slot * (32 * 256) + wid * (8 * 256);
#pragma unroll
  for (int zt = 0; zt < 8; ++zt) {
    float* dst = sp + zt * 256 + (lane >> 4) * 64 + (lane & 15);
#pragma unroll
    for (int r = 0; r < 4; ++r) dst[r * 16] = accs[zt][r];
  }
  if (t < L_DIM) {
    qpart[slot * 128 + t]         = sqseg[t];
    qpart[slot * 128 + L_DIM + t] = (float)cnt[t];
  }
}

// ---------------------------------------------------------------------------
// Reduce partial buffers
// gred[2][36][256], sred[2][4][4][8][256], qred[2][4][128]
// ---------------------------------------------------------------------------
__global__ void reduce_k(const float* __restrict__ gpart, const float* __restrict__ spart,
                         const float* __restrict__ qpart, float* __restrict__ gred,
                         float* __restrict__ sred, float* __restrict__ qred, int NB) {
  int id = blockIdx.x * blockDim.x + threadIdx.x;
  const int GE = 2 * 36 * 256, SE = 2 * 4 * 32 * 256, QE = 2 * 4 * 128;
  if (id < GE) {
    const int v = id / (36 * 256), e = id % (36 * 256);
    const float* p = gpart + (size_t)v * 4 * NB * (36 * 256) + e;
    float acc = 0.f;
    for (int s = 0; s < 4 * NB; ++s) acc += p[(size_t)s * (36 * 256)];
    gred[id] = acc;
  } else if ((id -= GE) < SE) {
    const int vb = id / (32 * 256);
    const float* p = spart + (size_t)vb * NB * (32 * 256) + (id % (32 * 256));
    float acc = 0.f;
    for (int s = 0; s < NB; ++s) acc += p[(size_t)s * (32 * 256)];
    sred[id] = acc;
  } else if ((id -= SE) < QE) {
    const int vb = id >> 7;
    const float* p = qpart + (size_t)vb * NB * 128 + (id & 127);
    float acc = 0.f;
    for (int s = 0; s < NB; ++s) acc += p[(size_t)s * 128];
    qred[id] = acc;
  }
}

// ---------------------------------------------------------------------------
// Finalize: sim + std + cov -> single scalar. 1 block x 256 threads, fp64 accum.
// sred index: (((v*4+b)*4 + (l>>4))*8 + (z>>4))*256 + (l&15)*16 + (z&15)
// qred index: (v*4+b)*128 + l  (sq sums) ; (v*4+b)*128 + 64 + l (counts)
// ---------------------------------------------------------------------------
__global__ void finalize_k(const float* __restrict__ gred, const float* __restrict__ sred,
                           const float* __restrict__ qred, float* __restrict__ out) {
  const int t = threadIdx.x;
  __shared__ double red[256];
  __shared__ double mu[2][128];
  __shared__ double scal[8];
  __shared__ int tti[36], ttj[36];
  if (t == 0) {
    int idx = 0;
    for (int ti = 0; ti < 8; ++ti)
      for (int tj = ti; tj < 8; ++tj) { tti[idx] = ti; ttj[idx] = tj; ++idx; }
  }
  const int bb = t >> 6, ll = t & 63;
  const double nlv = (double)qred[bb * 128 + 64 + ll];  // view0 counts

  red[t] = nlv;  // n
  __syncthreads();
  for (int s = 128; s > 0; s >>= 1) { if (t < s) red[t] += red[t + s]; __syncthreads(); }
  if (t == 0) scal[0] = red[0];
  __syncthreads();
  const double n = scal[0];

  red[t] = nlv * nlv;  // count
  __syncthreads();
  for (int s = 128; s > 0; s >>= 1) { if (t < s) red[t] += red[t + s]; __syncthreads(); }
  if (t == 0) scal[1] = red[0];
  __syncthreads();

  {  // sim numerator
    const double sqa = (double)qred[(0 * 4 + bb) * 128 + ll];
    const double sqm = (double)qred[(1 * 4 + bb) * 128 + ll];
    double dot = 0.0;
    for (int z = 0; z < 128; ++z) {
      const int e = ((ll & 15) << 4) + (z & 15);
      const int ia = (((0 * 4 + bb) * 4 + (ll >> 4)) * 8 + (z >> 4)) * 256 + e;
      const int im = (((1 * 4 + bb) * 4 + (ll >> 4)) * 8 + (z >> 4)) * 256 + e;
      dot += (double)sred[ia] * (double)sred[im];
    }
    red[t] = nlv * (sqa + sqm) - 2.0 * dot;
  }
  __syncthreads();
  for (int s = 128; s > 0; s >>= 1) { if (t < s) red[t] += red[t + s]; __syncthreads(); }
  if (t == 0) scal[2] = red[0];
  __syncthreads();

  {  // mu
    const int v = t >> 7, z = t & 127;
    double s = 0.0;
    for (int b = 0; b < 4; ++b)
      for (int l = 0; l < 64; ++l)
        s += (double)sred[(((v * 4 + b) * 4 + (l >> 4)) * 8 + (z >> 4)) * 256 + ((l & 15) << 4) + (z & 15)];
    mu[v][z] = s / n;
  }
  __syncthreads();

  {  // std
    const int v = t >> 7, z = t & 127;
    const int zt = z >> 4;
    const int lin = zt * 8 - (zt * (zt - 1)) / 2;
    const double gd = (double)gred[v * 9216 + lin * 256 + (z & 15) * 17];
    const double var = (gd - n * mu[v][z] * mu[v][z]) / (n - 1.0);
    const double sd = sqrt(var + 1e-4);
    const double rr = 1.0 - sd;
    red[t] = rr > 0.0 ? rr : 0.0;
  }
  __syncthreads();
  for (int s = 64; s > 0; s >>= 1) { if ((t & 127) < s) red[t] += red[t + s]; __syncthreads(); }
  if (t == 0)   scal[3] = red[0] / 128.0;
  if (t == 128) scal[4] = red[128] / 128.0;
  __syncthreads();

  for (int v = 0; v < 2; ++v) {  // cov: 2*sum_{i<j} cov_ij^2 / Z
    double acc = 0.0;
    for (int idx = t; idx < 9216; idx += 256) {
      const int lin = idx >> 8, e = idx & 255;
      const int i = tti[lin] * 16 + (e >> 4), j = ttj[lin] * 16 + (e & 15);
      if (i < j) {
        const double g = (double)gred[v * 9216 + idx];
        const double cv = (g - n * mu[v][i] * mu[v][j]) / (n - 1.0);
        acc += 2.0 * cv * cv;
      }
    }
    red[t] = acc;
    __syncthreads();
    for (int s = 128; s > 0; s >>= 1) { if (t < s) red[t] += red[t + s]; __syncthreads(); }
    if (t == 0) scal[5 + v] = red[0] / 128.0;
    __syncthreads();
  }

  if (t == 0)
    out[0] = (float)(scal[2] / scal[1] + scal[3] + scal[4] + scal[5] + scal[6]);
}

// ---------------------------------------------------------------------------
extern "C" void kernel_launch(void* const* d_in, const int* in_sizes, int n_in,
                              void* d_out, int out_size, void* d_ws, size_t ws_size,
                              hipStream_t stream) {
  const float*  pred   = (const float*)d_in[0];
  const float*  predmv = (const float*)d_in[1];
  const int*    gt     = (const int*)d_in[2];
  const uint8_t* fov   = (const uint8_t*)d_in[3];   // jnp bool = 1 byte/elem
  float* out = (float*)d_out;

  // NB = blocks per (view,batch). NB=32 -> grid 256 = 1 block/CU.
  int NB = 32;
  const size_t per_slot = 36 * 256 + 32 * 256 + 128;  // floats per block slot
  const size_t reserved = (size_t)(2 * 36 * 256 + 2 * 4 * 32 * 256 + 2 * 4 * 128) * 4 + 1024;
  while (NB > 16 && (size_t)8 * NB * per_slot * 4 + reserved > ws_size) NB >>= 1;

  float* ws    = (float*)d_ws;
  float* gpart = ws;
  float* spart = gpart + (size_t)8 * NB * (36 * 256);
  float* qpart = spart + (size_t)8 * NB * (32 * 256);
  float* gred  = qpart + (size_t)8 * NB * 128;
  float* sred  = gred + 2 * 36 * 256;
  float* qred  = sred + 2 * 4 * 32 * 256;

  const int nch = (P_DIM / NB) / CHUNK;
  pass1_k<<<dim3(NB, 4, 2), dim3(256), 0, stream>>>(pred, predmv, gt, fov,
                                                    gpart, spart, qpart, NB, nch);
  const int tot = 2 * 36 * 256 + 2 * 4 * 32 * 256 + 2 * 4 * 128;
  reduce_k<<<dim3((tot + 255) / 256), dim3(256), 0, stream>>>(gpart, spart, qpart,
                                                              gred, sred, qred, NB);
  finalize_k<<<dim3(1), dim3(256), 0, stream>>>(gred, sred, qred, out);
}